// Round 2
// baseline (12.391 us; speedup 1.0000x reference)
//
#include <hip/hip_runtime.h>
#include <hip/hip_bf16.h>

// out[b][o] = relu( bias[o] + sum_{s=0}^{4} W[o][s*1024 + loc[b][s]] )
// B=16384, SLOTS=5, ACTION_SIZE=1024, OUT=16, W is [16, 5120] row-major fp32.
//
// Two-phase:
//  1) transpose W [16][5120] -> Wt [5120][16] in d_ws (320 KB). Now the 16
//     output channels for one (slot,idx) are one 64B cache line.
//  2) gather: thread t = b*16 + o; per slot, 16-lane groups hit a single
//     line (4 lines/wave/slot instead of 64) -> 16x fewer VMEM transactions.

#define ACTION_SIZE 1024
#define SLOTS 5
#define OUT_CH 16
#define FAN_IN (SLOTS * ACTION_SIZE)   // 5120

__global__ __launch_bounds__(256) void transpose_w_kernel(
    const float* __restrict__ W,   // [16, 5120]
    float* __restrict__ Wt)        // [5120, 16]
{
    int t = blockIdx.x * 256 + threadIdx.x;   // 0 .. 81919
    int c = t >> 4;       // column of W (0..5119)
    int o = t & 15;       // output channel
    // write coalesced (Wt[t]), read line-grouped (16 lanes share c-group)
    Wt[t] = W[o * FAN_IN + c];
}

__global__ __launch_bounds__(256) void position_encode_kernel(
    const int* __restrict__ loc,   // [B, 5] int32
    const float* __restrict__ Wt,  // [5120, 16]
    const float* __restrict__ bias,// [16]
    float* __restrict__ out,       // [B, 16]
    int total)                     // B*16
{
    int t = blockIdx.x * 256 + threadIdx.x;
    if (t >= total) return;

    int row = t >> 4;        // batch index
    int o   = t & 15;        // output channel

    const int* l = loc + row * SLOTS;

    float acc = bias[o];
#pragma unroll
    for (int s = 0; s < SLOTS; ++s) {
        int idx = l[s];                       // broadcast across 16 lanes
        // Wt[(s*1024 + idx)*16 + o] : 16 lanes -> 16 consecutive floats
        acc += Wt[((s * ACTION_SIZE + idx) << 4) + o];
    }
    out[t] = fmaxf(acc, 0.0f);
}

extern "C" void kernel_launch(void* const* d_in, const int* in_sizes, int n_in,
                              void* d_out, int out_size, void* d_ws, size_t ws_size,
                              hipStream_t stream) {
    const int*   loc  = (const int*)d_in[0];    // [B,5] int32
    const float* W    = (const float*)d_in[1];  // [16,5120]
    const float* bias = (const float*)d_in[2];  // [16]
    float* out = (float*)d_out;
    float* Wt  = (float*)d_ws;                  // 5120*16*4 = 320 KB scratch

    // phase 1: transpose W into workspace (every call; deterministic)
    hipLaunchKernelGGL(transpose_w_kernel, dim3((FAN_IN * OUT_CH) / 256), dim3(256),
                       0, stream, W, Wt);

    // phase 2: gather + bias + relu
    int total = out_size;                       // B*16 = 262144
    int blocks = (total + 255) / 256;
    hipLaunchKernelGGL(position_encode_kernel, dim3(blocks), dim3(256), 0, stream,
                       loc, Wt, bias, out, total);
}

// Round 3
// 11.100 us; speedup vs baseline: 1.1163x; 1.1163x over previous
//
#include <hip/hip_runtime.h>
#include <hip/hip_bf16.h>

// out[b][o] = relu( bias[o] + sum_{s=0}^{4} W[o][s*1024 + loc[b][s]] )
// B=16384, SLOTS=5, ACTION_SIZE=1024, OUT=16, W row-major [16,5120] fp32.
//
// Single kernel (graph node overhead ~2us each dominates this 1.7 MB problem,
// so no separate transpose pass). Thread t = b*16 + o:
//   - block of 256 threads covers 16 rows; their 80 loc ints are staged
//     through LDS with one coalesced load (replaces 5 broadcast VMEM
//     loads/thread).
//   - W gathers: 64 lines/wave/slot is the original-layout minimum
//     (16 o-rows x 4 b's) — L2-resident, throughput-served.
//   - store: 4 B/lane fully coalesced.

#define ACTION_SIZE 1024
#define SLOTS 5
#define OUT_CH 16
#define FAN_IN (SLOTS * ACTION_SIZE)   // 5120
#define ROWS_PER_BLOCK 16              // 256 threads / 16 o

__global__ __launch_bounds__(256) void position_encode_kernel(
    const int* __restrict__ loc,   // [B, 5] int32
    const float* __restrict__ W,   // [16, 5120]
    const float* __restrict__ bias,// [16]
    float* __restrict__ out)       // [B, 16]
{
    __shared__ int s_loc[ROWS_PER_BLOCK * SLOTS];   // 80 ints

    int tid = threadIdx.x;
    int block_row0 = blockIdx.x * ROWS_PER_BLOCK;

    if (tid < ROWS_PER_BLOCK * SLOTS)
        s_loc[tid] = loc[block_row0 * SLOTS + tid];
    __syncthreads();

    int row_local = tid >> 4;      // 0..15
    int o         = tid & 15;      // output channel

    const float* wrow = W + o * FAN_IN;
    const int* l = s_loc + row_local * SLOTS;

    float acc = bias[o];
#pragma unroll
    for (int s = 0; s < SLOTS; ++s) {
        acc += wrow[s * ACTION_SIZE + l[s]];
    }
    out[(block_row0 + row_local) * OUT_CH + o] = fmaxf(acc, 0.0f);
}

extern "C" void kernel_launch(void* const* d_in, const int* in_sizes, int n_in,
                              void* d_out, int out_size, void* d_ws, size_t ws_size,
                              hipStream_t stream) {
    const int*   loc  = (const int*)d_in[0];    // [B,5] int32
    const float* W    = (const float*)d_in[1];  // [16,5120]
    const float* bias = (const float*)d_in[2];  // [16]
    float* out = (float*)d_out;

    int total  = out_size;                      // B*16 = 262144
    int blocks = total / 256;                   // 1024, exact
    hipLaunchKernelGGL(position_encode_kernel, dim3(blocks), dim3(256), 0, stream,
                       loc, W, bias, out);
}